// Round 4
// baseline (226.404 us; speedup 1.0000x reference)
//
#include <hip/hip_runtime.h>

typedef unsigned short u16;
typedef unsigned int u32;
typedef __attribute__((ext_vector_type(8))) short bf16x8;
typedef __attribute__((ext_vector_type(4))) float f32x4;

__device__ __forceinline__ u16 f2bf(float f) {
    u32 u = __float_as_uint(f);
    u += 0x7fffu + ((u >> 16) & 1u);
    return (u16)(u >> 16);
}

// async global->LDS DMA, 16B per lane, LDS dest = wave-uniform base + lane*16
#define GL2LDS(gp, lp)                                                                 \
    __builtin_amdgcn_global_load_lds((const __attribute__((address_space(1))) u32*)(const void*)(gp), \
                                     (__attribute__((address_space(3))) u32*)(void*)(lp), 16, 0, 0)

// ---------------- cast fp32 -> bf16 (vectorized x4) ----------------
__global__ __launch_bounds__(256) void cast_kernel(const float* __restrict__ src,
                                                   u16* __restrict__ dst, int n4) {
    int i = blockIdx.x * 256 + threadIdx.x;
    if (i >= n4) return;
    float4 val = ((const float4*)src)[i];
    uint2 o;
    o.x = ((u32)f2bf(val.y) << 16) | f2bf(val.x);
    o.y = ((u32)f2bf(val.w) << 16) | f2bf(val.z);
    ((uint2*)dst)[i] = o;
}

// ---------------- transpose+cast all 4 weight matrices in one launch ----------------
__global__ __launch_bounds__(256) void transpose4(const float* __restrict__ Wq,
                                                  const float* __restrict__ Wk,
                                                  const float* __restrict__ Wv,
                                                  const float* __restrict__ Wo,
                                                  u16* __restrict__ Wcat,
                                                  u16* __restrict__ Wot) {
    __shared__ float tl[32][33];
    const int zi = blockIdx.z;
    const float* src = (zi == 0) ? Wq : (zi == 1) ? Wk : (zi == 2) ? Wv : Wo;
    u16* dst = (zi < 3) ? (Wcat + zi * 1048576) : Wot;
    const int tx = threadIdx.x & 31, ty = threadIdx.x >> 5;
    const int kt = blockIdx.y * 32, nt = blockIdx.x * 32;
#pragma unroll
    for (int j = 0; j < 4; ++j)
        tl[ty + j * 8][tx] = src[(kt + ty + j * 8) * 1024 + nt + tx];
    __syncthreads();
#pragma unroll
    for (int j = 0; j < 4; ++j)
        dst[(nt + ty + j * 8) * 1024 + kt + tx] = f2bf(tl[tx][ty + j * 8]);
}

// ---------------- R_hat table: tab[h][dist] = (1+e^v)/(1+e^(v-w*dist)) / sqrt(64) --------
__global__ __launch_bounds__(256) void rtab_kernel(const float* __restrict__ wp,
                                                   const float* __restrict__ vp,
                                                   float* __restrict__ tab) {
    const int i = blockIdx.x * 256 + threadIdx.x;  // 16*2048
    const int h = i >> 11, d = i & 2047;
    const float vv = vp[h], ww = wp[h];
    tab[i] = (1.f + expf(vv)) / (1.f + expf(vv - ww * (float)d)) * 0.125f;
}

// ---------------- m97-style bf16 MFMA GEMM: 128xBN tile, BK=64, global_load_lds ------
// C = A[M][K] @ Bt[N][K]^T.  LDS tiles unpadded, XOR-swizzled (chunk ^= row&7).
// MODE 0: fp32 out + bias.  MODE 1: col<2048 -> Cb bf16 [M][2048]; else Vtb bf16 [col-2048][M].
template <int MODE, int BN>
__global__ __launch_bounds__(256, 3) void gemm128(const u16* __restrict__ A,
                                                  const u16* __restrict__ Bt,
                                                  float* __restrict__ C,
                                                  const float* __restrict__ bias,
                                                  u16* __restrict__ Cb,
                                                  u16* __restrict__ Vtb,
                                                  int M, int N, int K) {
    constexpr int NBW = BN / 32;  // 16-wide n-blocks per wave
    __shared__ __align__(16) u16 As[8192];      // 128 rows x 64
    __shared__ __align__(16) u16 Bs[BN * 64];   // BN rows x 64
    const int t = threadIdx.x, lane = t & 63, wv = t >> 6;
    const int l15 = lane & 15, quad = lane >> 4;
    const int m0 = blockIdx.y << 7, n0 = blockIdx.x * BN;
    const int wm = (wv & 1) << 6, wn = (wv >> 1) * (BN / 2);

    f32x4 acc[4][NBW];
#pragma unroll
    for (int i = 0; i < 4; ++i)
#pragma unroll
        for (int j = 0; j < NBW; ++j) acc[i][j] = (f32x4){0.f, 0.f, 0.f, 0.f};

    const int lrow = lane >> 3, lchunk = lane & 7;
    for (int k0 = 0; k0 < K; k0 += 64) {
#pragma unroll
        for (int c = 0; c < 4; ++c) {  // A: 128 rows
            const int r0 = wv * 32 + c * 8;
            const int row = r0 + lrow;
            const int g = lchunk ^ (row & 7);
            GL2LDS(A + (size_t)(m0 + row) * K + k0 + g * 8, &As[r0 * 64]);
        }
#pragma unroll
        for (int c = 0; c < BN / 32; ++c) {  // B: BN rows
            const int r0 = wv * (BN / 4) + c * 8;
            const int row = r0 + lrow;
            const int g = lchunk ^ (row & 7);
            GL2LDS(Bt + (size_t)(n0 + row) * K + k0 + g * 8, &Bs[r0 * 64]);
        }
        __syncthreads();  // drains global_load_lds (vmcnt) + protects prior reads
#pragma unroll
        for (int ks = 0; ks < 2; ++ks) {
            const int p = ((ks << 2) | quad) ^ (l15 & 7);
            bf16x8 af[4], bfr[NBW];
#pragma unroll
            for (int i = 0; i < 4; ++i)
                af[i] = *(const bf16x8*)&As[(wm + i * 16 + l15) * 64 + p * 8];
#pragma unroll
            for (int j = 0; j < NBW; ++j)
                bfr[j] = *(const bf16x8*)&Bs[(wn + j * 16 + l15) * 64 + p * 8];
#pragma unroll
            for (int mb = 0; mb < 4; ++mb)
#pragma unroll
                for (int nb = 0; nb < NBW; ++nb)
                    acc[mb][nb] = __builtin_amdgcn_mfma_f32_16x16x32_bf16(af[mb], bfr[nb],
                                                                          acc[mb][nb], 0, 0, 0);
        }
        __syncthreads();  // protect LDS before next stage overwrites
    }
    // epilogue: C/D layout col=lane&15, row=(lane>>4)*4+reg
    const int rb = m0 + wm + (quad << 2);
    const int cbase = n0 + wn + l15;
#pragma unroll
    for (int mb = 0; mb < 4; ++mb)
#pragma unroll
        for (int nb = 0; nb < NBW; ++nb) {
            const int col = cbase + nb * 16;
#pragma unroll
            for (int r = 0; r < 4; ++r) {
                const int row = rb + mb * 16 + r;
                if (MODE == 0) {
                    C[(size_t)row * N + col] = acc[mb][nb][r] + bias[col];
                } else {
                    if (col < 2048)
                        Cb[(size_t)row * 2048 + col] = f2bf(acc[mb][nb][r]);
                    else
                        Vtb[(size_t)(col - 2048) * 4096 + row] = f2bf(acc[mb][nb][r]);
                }
            }
        }
}

// ---------------- MFMA flash attention v3: one q-tile/block, 3 blocks/CU ----
// qkb: bf16 [4096][2048] (Q | K per row).  vtb: bf16 [1024][4096] (V^T).
// Wave w owns k-col slice w*16 (for S) and d-slice w*16 (for PV). P is block-shared.
// Softmax max fixed at 0 (scores >= 0); l deferred to epilogue.
// Off-diagonal tiles skip causal masking (dist >= 1 provable). P stored truncated bf16.
__global__ __launch_bounds__(256, 3) void attn_kernel(const u16* __restrict__ qkb,
                                                      const u16* __restrict__ vtb,
                                                      const float* __restrict__ rtab,
                                                      u16* __restrict__ ctxb) {
    __shared__ __align__(16) u16 Kt[2][4096];   // [kseq][d] swizzled, 8KB x2
    __shared__ __align__(16) u16 Vt2[2][4096];  // [d][kseq] swizzled, 8KB x2
    __shared__ __align__(16) u16 Ps[64][76];    // block-shared P [q][kseq], padded
    __shared__ float rall[2048];                // R_hat/8 row for this head
    __shared__ float lred[4][64];

    const int t = threadIdx.x, lane = t & 63, wv = t >> 6;
    const int l15 = lane & 15, quad = lane >> 4;
    const int qt = 31 - blockIdx.x;             // longest-first dispatch
    const int bh = blockIdx.y;
    const int b = bh >> 4, h = bh & 15;
    const int q0 = qt << 6;

    for (int i = t; i < q0 + 64; i += 256) rall[i] = rtab[(h << 11) + i];

    const int lrow = lane >> 3, lchunk = lane & 7;
    const int half0 = (wv & 1) * 32;

    // Q fragments (A operand, all 64 q rows): m = mb*16+l15, k = ks*32+quad*8
    bf16x8 qa[4][2];
#pragma unroll
    for (int mb = 0; mb < 4; ++mb) {
        const u16* qrow = qkb + (size_t)(b * 2048 + q0 + mb * 16 + l15) * 2048 +
                          (h << 6) + quad * 8;
        qa[mb][0] = *(const bf16x8*)(qrow);
        qa[mb][1] = *(const bf16x8*)(qrow + 32);
    }

    f32x4 cacc[4];
#pragma unroll
    for (int i = 0; i < 4; ++i) cacc[i] = (f32x4){0.f, 0.f, 0.f, 0.f};
    float lacc[4][4] = {};

    // stage kt=0 into buffer 0
#pragma unroll
    for (int c = 0; c < 4; ++c) {
        const int r0 = half0 + c * 8;
        const int row = r0 + lrow;
        const int g = lchunk ^ (row & 7);
        if (wv < 2)
            GL2LDS(qkb + (size_t)(b * 2048 + row) * 2048 + 1024 + (h << 6) + g * 8,
                   &Kt[0][r0 * 64]);
        else
            GL2LDS(vtb + (size_t)((h << 6) + row) * 4096 + b * 2048 + g * 8,
                   &Vt2[0][r0 * 64]);
    }

    for (int kt = 0; kt <= qt; ++kt) {
        const int bsel = kt & 1;
        __syncthreads();  // drains staging of buf[bsel]; Ps safe to rewrite
        if (kt < qt) {    // prefetch kt+1 into other buffer
            const int kg0 = (kt + 1) << 6;
#pragma unroll
            for (int c = 0; c < 4; ++c) {
                const int r0 = half0 + c * 8;
                const int row = r0 + lrow;
                const int g = lchunk ^ (row & 7);
                if (wv < 2)
                    GL2LDS(qkb + (size_t)(b * 2048 + kg0 + row) * 2048 + 1024 + (h << 6) + g * 8,
                           &Kt[bsel ^ 1][r0 * 64]);
                else
                    GL2LDS(vtb + (size_t)((h << 6) + row) * 4096 + b * 2048 + kg0 + g * 8,
                           &Vt2[bsel ^ 1][r0 * 64]);
            }
        }

        // ---- S = Q @ K^T : wave's 16-col slice, all 64 q rows (8 MFMA) ----
        f32x4 sacc[4];
#pragma unroll
        for (int i = 0; i < 4; ++i) sacc[i] = (f32x4){0.f, 0.f, 0.f, 0.f};
#pragma unroll
        for (int ks = 0; ks < 2; ++ks) {
            const int p = ((ks << 2) | quad) ^ (l15 & 7);
            bf16x8 kb = *(const bf16x8*)&Kt[bsel][((wv << 4) + l15) * 64 + p * 8];
#pragma unroll
            for (int mb = 0; mb < 4; ++mb)
                sacc[mb] = __builtin_amdgcn_mfma_f32_16x16x32_bf16(qa[mb][ks], kb,
                                                                   sacc[mb], 0, 0, 0);
        }

        // ---- gate + exp (fixed m=0) + lacc + P write (truncating bf16) ----
        // row = q0+mb*16+quad*4+r (C layout), col = kt*64 + wv*16 + l15
        const int dbase = q0 - ((kt << 6) + (wv << 4) + l15);
        if (kt < qt) {  // off-diagonal: dist >= 1 guaranteed, no masking
#pragma unroll
            for (int mb = 0; mb < 4; ++mb)
#pragma unroll
                for (int r = 0; r < 4; ++r) {
                    const int dist = dbase + mb * 16 + (quad << 2) + r;
                    const float pe = __expf(fmaxf(sacc[mb][r], 0.f) * rall[dist]);
                    lacc[mb][r] += pe;
                    Ps[mb * 16 + (quad << 2) + r][(wv << 4) + l15] =
                        (u16)(__float_as_uint(pe) >> 16);
                }
        } else {  // diagonal tile: causal mask
#pragma unroll
            for (int mb = 0; mb < 4; ++mb)
#pragma unroll
                for (int r = 0; r < 4; ++r) {
                    const int dist = dbase + mb * 16 + (quad << 2) + r;
                    const int di = dist < 0 ? 0 : dist;
                    float pe = __expf(fmaxf(sacc[mb][r], 0.f) * rall[di]);
                    pe = (dist < 0) ? 0.f : pe;
                    lacc[mb][r] += pe;
                    Ps[mb * 16 + (quad << 2) + r][(wv << 4) + l15] =
                        (u16)(__float_as_uint(pe) >> 16);
                }
        }
        __syncthreads();  // Ps visible to all waves

        // ---- ctx += P @ V : wave's 16-wide d-slice, all 64 q rows (8 MFMA) ----
#pragma unroll
        for (int ks = 0; ks < 2; ++ks) {
            const int p = ((ks << 2) | quad) ^ (l15 & 7);
            bf16x8 vb = *(const bf16x8*)&Vt2[bsel][((wv << 4) + l15) * 64 + p * 8];
#pragma unroll
            for (int mb = 0; mb < 4; ++mb) {
                bf16x8 pa = *(const bf16x8*)&Ps[mb * 16 + l15][ks * 32 + quad * 8];
                cacc[mb] = __builtin_amdgcn_mfma_f32_16x16x32_bf16(pa, vb,
                                                                   cacc[mb], 0, 0, 0);
            }
        }
    }

    // ---- epilogue: reduce l across lanes (cols) then waves; normalize; store ----
#pragma unroll
    for (int off = 1; off < 16; off <<= 1)
#pragma unroll
        for (int mb = 0; mb < 4; ++mb)
#pragma unroll
            for (int r = 0; r < 4; ++r)
                lacc[mb][r] += __shfl_xor(lacc[mb][r], off, 16);
    if (l15 == 0) {
#pragma unroll
        for (int mb = 0; mb < 4; ++mb)
#pragma unroll
            for (int r = 0; r < 4; ++r)
                lred[wv][mb * 16 + (quad << 2) + r] = lacc[mb][r];
    }
    __syncthreads();
#pragma unroll
    for (int mb = 0; mb < 4; ++mb)
#pragma unroll
        for (int r = 0; r < 4; ++r) {
            const int row = mb * 16 + (quad << 2) + r;
            const float lt = (lred[0][row] + lred[1][row]) + (lred[2][row] + lred[3][row]);
            const float o = cacc[mb][r] / lt;
            ctxb[(size_t)(b * 2048 + q0 + row) * 1024 + (h << 6) + (wv << 4) + l15] = f2bf(o);
        }
}

extern "C" void kernel_launch(void* const* d_in, const int* in_sizes, int n_in,
                              void* d_out, int out_size, void* d_ws, size_t ws_size,
                              hipStream_t stream) {
    const float* x  = (const float*)d_in[0];
    const float* Wq = (const float*)d_in[1];
    const float* Wk = (const float*)d_in[2];
    const float* Wv = (const float*)d_in[3];
    const float* Wo = (const float*)d_in[4];
    const float* bo = (const float*)d_in[5];
    const float* w  = (const float*)d_in[6];
    const float* v  = (const float*)d_in[7];
    float* out = (float*)d_out;

    char* w8 = (char*)d_ws;
    u16*  xb   = (u16*)(w8);                     //  8 MB : x bf16 [4096][1024]
    u16*  Wcat = (u16*)(w8 + (8u << 20));        //  6 MB : (Wq|Wk|Wv)^T bf16 [3072][1024]
    u16*  Wot  = (u16*)(w8 + (14u << 20));       //  2 MB : Wo^T bf16 [1024][1024]
    u16*  qkb  = (u16*)(w8 + (16u << 20));       // 16 MB : Q|K bf16 [4096][2048]
    u16*  vtb  = (u16*)(w8 + (32u << 20));       //  8 MB : V^T bf16 [1024][4096]
    u16*  ctxb = (u16*)(w8 + (40u << 20));       //  8 MB : ctx bf16 [4096][1024]
    float* rtab = (float*)(w8 + (48u << 20));    // 128 KB: R_hat/8 [16][2048]

    cast_kernel<<<4096, 256, 0, stream>>>(x, xb, 1048576);
    transpose4<<<dim3(32, 32, 4), 256, 0, stream>>>(Wq, Wk, Wv, Wo, Wcat, Wot);
    rtab_kernel<<<128, 256, 0, stream>>>(w, v, rtab);

    // QKV fused projection -> bf16 qkb + transposed V   [M=4096, N=3072, K=1024]
    gemm128<1, 128><<<dim3(24, 32), 256, 0, stream>>>(xb, Wcat, nullptr, nullptr, qkb, vtb,
                                                      4096, 3072, 1024);
    // MFMA flash attention (one q-tile per block, longest-first)
    attn_kernel<<<dim3(32, 32), 256, 0, stream>>>(qkb, vtb, rtab, ctxb);
    // output projection + bias (fp32 out)   [M=4096, N=1024, K=1024], 128x64 tiles
    gemm128<0, 64><<<dim3(16, 32), 256, 0, stream>>>(ctxb, Wot, out, bo, nullptr, nullptr,
                                                     4096, 1024, 1024);
}

// Round 5
// 196.644 us; speedup vs baseline: 1.1513x; 1.1513x over previous
//
#include <hip/hip_runtime.h>

typedef unsigned short u16;
typedef unsigned int u32;
typedef __attribute__((ext_vector_type(8))) short bf16x8;
typedef __attribute__((ext_vector_type(4))) float f32x4;

__device__ __forceinline__ u16 f2bf(float f) {
    u32 u = __float_as_uint(f);
    u += 0x7fffu + ((u >> 16) & 1u);
    return (u16)(u >> 16);
}

// async global->LDS DMA, 16B per lane, LDS dest = wave-uniform base + lane*16
#define GL2LDS(gp, lp)                                                                 \
    __builtin_amdgcn_global_load_lds((const __attribute__((address_space(1))) u32*)(const void*)(gp), \
                                     (__attribute__((address_space(3))) u32*)(void*)(lp), 16, 0, 0)

// ---------------- cast fp32 -> bf16 (vectorized x4) ----------------
__global__ __launch_bounds__(256) void cast_kernel(const float* __restrict__ src,
                                                   u16* __restrict__ dst, int n4) {
    int i = blockIdx.x * 256 + threadIdx.x;
    if (i >= n4) return;
    float4 val = ((const float4*)src)[i];
    uint2 o;
    o.x = ((u32)f2bf(val.y) << 16) | f2bf(val.x);
    o.y = ((u32)f2bf(val.w) << 16) | f2bf(val.z);
    ((uint2*)dst)[i] = o;
}

// ---------------- transpose+cast all 4 weight matrices in one launch ----------------
__global__ __launch_bounds__(256) void transpose4(const float* __restrict__ Wq,
                                                  const float* __restrict__ Wk,
                                                  const float* __restrict__ Wv,
                                                  const float* __restrict__ Wo,
                                                  u16* __restrict__ Wcat,
                                                  u16* __restrict__ Wot) {
    __shared__ float tl[32][33];
    const int zi = blockIdx.z;
    const float* src = (zi == 0) ? Wq : (zi == 1) ? Wk : (zi == 2) ? Wv : Wo;
    u16* dst = (zi < 3) ? (Wcat + zi * 1048576) : Wot;
    const int tx = threadIdx.x & 31, ty = threadIdx.x >> 5;
    const int kt = blockIdx.y * 32, nt = blockIdx.x * 32;
#pragma unroll
    for (int j = 0; j < 4; ++j)
        tl[ty + j * 8][tx] = src[(kt + ty + j * 8) * 1024 + nt + tx];
    __syncthreads();
#pragma unroll
    for (int j = 0; j < 4; ++j)
        dst[(nt + ty + j * 8) * 1024 + kt + tx] = f2bf(tl[tx][ty + j * 8]);
}

// ------- R_hat table: tab[h][dist] = (1+e^v)/(1+e^(v-w*dist))/sqrt(64); also zeroes job counter -----
__global__ __launch_bounds__(256) void rtab_kernel(const float* __restrict__ wp,
                                                   const float* __restrict__ vp,
                                                   float* __restrict__ tab,
                                                   u32* __restrict__ counter) {
    const int i = blockIdx.x * 256 + threadIdx.x;  // 16*2048
    if (i == 0) counter[0] = 0u;                   // work-stealing counter for attn
    const int h = i >> 11, d = i & 2047;
    const float vv = vp[h], ww = wp[h];
    tab[i] = (1.f + expf(vv)) / (1.f + expf(vv - ww * (float)d)) * 0.125f;
}

// ---------------- m97-style bf16 MFMA GEMM: 128xBN tile, BK=64, global_load_lds ------
// C = A[M][K] @ Bt[N][K]^T.  LDS tiles unpadded, XOR-swizzled (chunk ^= row&7).
// MODE 0: fp32 out + bias.  MODE 1: col<2048 -> Cb bf16 [M][2048]; else Vtb bf16 [col-2048][M].
template <int MODE, int BN>
__global__ __launch_bounds__(256, 3) void gemm128(const u16* __restrict__ A,
                                                  const u16* __restrict__ Bt,
                                                  float* __restrict__ C,
                                                  const float* __restrict__ bias,
                                                  u16* __restrict__ Cb,
                                                  u16* __restrict__ Vtb,
                                                  int M, int N, int K) {
    constexpr int NBW = BN / 32;  // 16-wide n-blocks per wave
    __shared__ __align__(16) u16 As[8192];      // 128 rows x 64
    __shared__ __align__(16) u16 Bs[BN * 64];   // BN rows x 64
    const int t = threadIdx.x, lane = t & 63, wv = t >> 6;
    const int l15 = lane & 15, quad = lane >> 4;
    const int m0 = blockIdx.y << 7, n0 = blockIdx.x * BN;
    const int wm = (wv & 1) << 6, wn = (wv >> 1) * (BN / 2);

    f32x4 acc[4][NBW];
#pragma unroll
    for (int i = 0; i < 4; ++i)
#pragma unroll
        for (int j = 0; j < NBW; ++j) acc[i][j] = (f32x4){0.f, 0.f, 0.f, 0.f};

    const int lrow = lane >> 3, lchunk = lane & 7;
    for (int k0 = 0; k0 < K; k0 += 64) {
#pragma unroll
        for (int c = 0; c < 4; ++c) {  // A: 128 rows
            const int r0 = wv * 32 + c * 8;
            const int row = r0 + lrow;
            const int g = lchunk ^ (row & 7);
            GL2LDS(A + (size_t)(m0 + row) * K + k0 + g * 8, &As[r0 * 64]);
        }
#pragma unroll
        for (int c = 0; c < BN / 32; ++c) {  // B: BN rows
            const int r0 = wv * (BN / 4) + c * 8;
            const int row = r0 + lrow;
            const int g = lchunk ^ (row & 7);
            GL2LDS(Bt + (size_t)(n0 + row) * K + k0 + g * 8, &Bs[r0 * 64]);
        }
        __syncthreads();  // drains global_load_lds (vmcnt) + protects prior reads
#pragma unroll
        for (int ks = 0; ks < 2; ++ks) {
            const int p = ((ks << 2) | quad) ^ (l15 & 7);
            bf16x8 af[4], bfr[NBW];
#pragma unroll
            for (int i = 0; i < 4; ++i)
                af[i] = *(const bf16x8*)&As[(wm + i * 16 + l15) * 64 + p * 8];
#pragma unroll
            for (int j = 0; j < NBW; ++j)
                bfr[j] = *(const bf16x8*)&Bs[(wn + j * 16 + l15) * 64 + p * 8];
#pragma unroll
            for (int mb = 0; mb < 4; ++mb)
#pragma unroll
                for (int nb = 0; nb < NBW; ++nb)
                    acc[mb][nb] = __builtin_amdgcn_mfma_f32_16x16x32_bf16(af[mb], bfr[nb],
                                                                          acc[mb][nb], 0, 0, 0);
        }
        __syncthreads();  // protect LDS before next stage overwrites
    }
    // epilogue: C/D layout col=lane&15, row=(lane>>4)*4+reg
    const int rb = m0 + wm + (quad << 2);
    const int cbase = n0 + wn + l15;
#pragma unroll
    for (int mb = 0; mb < 4; ++mb)
#pragma unroll
        for (int nb = 0; nb < NBW; ++nb) {
            const int col = cbase + nb * 16;
#pragma unroll
            for (int r = 0; r < 4; ++r) {
                const int row = rb + mb * 16 + r;
                if (MODE == 0) {
                    C[(size_t)row * N + col] = acc[mb][nb][r] + bias[col];
                } else {
                    if (col < 2048)
                        Cb[(size_t)row * 2048 + col] = f2bf(acc[mb][nb][r]);
                    else
                        Vtb[(size_t)(col - 2048) * 4096 + row] = f2bf(acc[mb][nb][r]);
                }
            }
        }
}

// ---------------- MFMA flash attention v4: persistent blocks + work stealing ----
// 768 blocks (3/CU), jobs = (bh, qt) pulled from atomic counter, longest-first:
// job j -> qt = 31 - (j>>5), bh = j&31.  Per-job body identical to v3.
// qkb: bf16 [4096][2048] (Q | K).  vtb: bf16 [1024][4096] (V^T).
__global__ __launch_bounds__(256, 3) void attn_kernel(const u16* __restrict__ qkb,
                                                      const u16* __restrict__ vtb,
                                                      const float* __restrict__ rtab,
                                                      u16* __restrict__ ctxb,
                                                      u32* __restrict__ counter) {
    __shared__ __align__(16) u16 Kt[2][4096];   // [kseq][d] swizzled, 8KB x2
    __shared__ __align__(16) u16 Vt2[2][4096];  // [d][kseq] swizzled, 8KB x2
    __shared__ __align__(16) u16 Ps[64][76];    // block-shared P [q][kseq], padded
    __shared__ float rall[2048];                // R_hat/8 row for this head
    __shared__ float lred[4][64];
    __shared__ int jobS;

    const int t = threadIdx.x, lane = t & 63, wv = t >> 6;
    const int l15 = lane & 15, quad = lane >> 4;
    const int lrow = lane >> 3, lchunk = lane & 7;
    const int half0 = (wv & 1) * 32;

    for (;;) {
        if (t == 0) jobS = (int)atomicAdd(counter, 1u);
        __syncthreads();       // jobS visible; also fences prior job's LDS reads
        const int job = jobS;
        if (job >= 1024) break;
        const int qt = 31 - (job >> 5);       // longest jobs first
        const int bh = job & 31;
        const int b = bh >> 4, h = bh & 15;
        const int q0 = qt << 6;

        for (int i = t; i < q0 + 64; i += 256) rall[i] = rtab[(h << 11) + i];

        // Q fragments (A operand, all 64 q rows): m = mb*16+l15, k = ks*32+quad*8
        bf16x8 qa[4][2];
#pragma unroll
        for (int mb = 0; mb < 4; ++mb) {
            const u16* qrow = qkb + (size_t)(b * 2048 + q0 + mb * 16 + l15) * 2048 +
                              (h << 6) + quad * 8;
            qa[mb][0] = *(const bf16x8*)(qrow);
            qa[mb][1] = *(const bf16x8*)(qrow + 32);
        }

        f32x4 cacc[4];
#pragma unroll
        for (int i = 0; i < 4; ++i) cacc[i] = (f32x4){0.f, 0.f, 0.f, 0.f};
        float lacc[4][4] = {};

        // stage kt=0 into buffer 0
#pragma unroll
        for (int c = 0; c < 4; ++c) {
            const int r0 = half0 + c * 8;
            const int row = r0 + lrow;
            const int g = lchunk ^ (row & 7);
            if (wv < 2)
                GL2LDS(qkb + (size_t)(b * 2048 + row) * 2048 + 1024 + (h << 6) + g * 8,
                       &Kt[0][r0 * 64]);
            else
                GL2LDS(vtb + (size_t)((h << 6) + row) * 4096 + b * 2048 + g * 8,
                       &Vt2[0][r0 * 64]);
        }

        for (int kt = 0; kt <= qt; ++kt) {
            const int bsel = kt & 1;
            __syncthreads();  // drains staging of buf[bsel]; Ps/rall safe & visible
            if (kt < qt) {    // prefetch kt+1 into other buffer
                const int kg0 = (kt + 1) << 6;
#pragma unroll
                for (int c = 0; c < 4; ++c) {
                    const int r0 = half0 + c * 8;
                    const int row = r0 + lrow;
                    const int g = lchunk ^ (row & 7);
                    if (wv < 2)
                        GL2LDS(qkb + (size_t)(b * 2048 + kg0 + row) * 2048 + 1024 + (h << 6) + g * 8,
                               &Kt[bsel ^ 1][r0 * 64]);
                    else
                        GL2LDS(vtb + (size_t)((h << 6) + row) * 4096 + b * 2048 + kg0 + g * 8,
                               &Vt2[bsel ^ 1][r0 * 64]);
                }
            }

            // ---- S = Q @ K^T : wave's 16-col slice, all 64 q rows (8 MFMA) ----
            f32x4 sacc[4];
#pragma unroll
            for (int i = 0; i < 4; ++i) sacc[i] = (f32x4){0.f, 0.f, 0.f, 0.f};
#pragma unroll
            for (int ks = 0; ks < 2; ++ks) {
                const int p = ((ks << 2) | quad) ^ (l15 & 7);
                bf16x8 kb = *(const bf16x8*)&Kt[bsel][((wv << 4) + l15) * 64 + p * 8];
#pragma unroll
                for (int mb = 0; mb < 4; ++mb)
                    sacc[mb] = __builtin_amdgcn_mfma_f32_16x16x32_bf16(qa[mb][ks], kb,
                                                                       sacc[mb], 0, 0, 0);
            }

            // ---- gate + exp (fixed m=0) + lacc + P write (truncating bf16) ----
            // row = q0+mb*16+quad*4+r (C layout), col = kt*64 + wv*16 + l15
            const int dbase = q0 - ((kt << 6) + (wv << 4) + l15);
            if (kt < qt) {  // off-diagonal: dist >= 1 guaranteed, no masking
#pragma unroll
                for (int mb = 0; mb < 4; ++mb)
#pragma unroll
                    for (int r = 0; r < 4; ++r) {
                        const int dist = dbase + mb * 16 + (quad << 2) + r;
                        const float pe = __expf(fmaxf(sacc[mb][r], 0.f) * rall[dist]);
                        lacc[mb][r] += pe;
                        Ps[mb * 16 + (quad << 2) + r][(wv << 4) + l15] =
                            (u16)(__float_as_uint(pe) >> 16);
                    }
            } else {  // diagonal tile: causal mask
#pragma unroll
                for (int mb = 0; mb < 4; ++mb)
#pragma unroll
                    for (int r = 0; r < 4; ++r) {
                        const int dist = dbase + mb * 16 + (quad << 2) + r;
                        const int di = dist < 0 ? 0 : dist;
                        float pe = __expf(fmaxf(sacc[mb][r], 0.f) * rall[di]);
                        pe = (dist < 0) ? 0.f : pe;
                        lacc[mb][r] += pe;
                        Ps[mb * 16 + (quad << 2) + r][(wv << 4) + l15] =
                            (u16)(__float_as_uint(pe) >> 16);
                    }
            }
            __syncthreads();  // Ps visible to all waves

            // ---- ctx += P @ V : wave's 16-wide d-slice, all 64 q rows (8 MFMA) ----
#pragma unroll
            for (int ks = 0; ks < 2; ++ks) {
                const int p = ((ks << 2) | quad) ^ (l15 & 7);
                bf16x8 vb = *(const bf16x8*)&Vt2[bsel][((wv << 4) + l15) * 64 + p * 8];
#pragma unroll
                for (int mb = 0; mb < 4; ++mb) {
                    bf16x8 pa = *(const bf16x8*)&Ps[mb * 16 + l15][ks * 32 + quad * 8];
                    cacc[mb] = __builtin_amdgcn_mfma_f32_16x16x32_bf16(pa, vb,
                                                                       cacc[mb], 0, 0, 0);
                }
            }
        }

        // ---- epilogue: reduce l across lanes then waves; normalize; store ----
#pragma unroll
        for (int off = 1; off < 16; off <<= 1)
#pragma unroll
            for (int mb = 0; mb < 4; ++mb)
#pragma unroll
                for (int r = 0; r < 4; ++r)
                    lacc[mb][r] += __shfl_xor(lacc[mb][r], off, 16);
        if (l15 == 0) {
#pragma unroll
            for (int mb = 0; mb < 4; ++mb)
#pragma unroll
                for (int r = 0; r < 4; ++r)
                    lred[wv][mb * 16 + (quad << 2) + r] = lacc[mb][r];
        }
        __syncthreads();
#pragma unroll
        for (int mb = 0; mb < 4; ++mb)
#pragma unroll
            for (int r = 0; r < 4; ++r) {
                const int row = mb * 16 + (quad << 2) + r;
                const float lt = (lred[0][row] + lred[1][row]) + (lred[2][row] + lred[3][row]);
                const float o = cacc[mb][r] / lt;
                ctxb[(size_t)(b * 2048 + q0 + row) * 1024 + (h << 6) + (wv << 4) + l15] = f2bf(o);
            }
        // loop-top __syncthreads() fences these LDS reads before next job's writes
    }
}

extern "C" void kernel_launch(void* const* d_in, const int* in_sizes, int n_in,
                              void* d_out, int out_size, void* d_ws, size_t ws_size,
                              hipStream_t stream) {
    const float* x  = (const float*)d_in[0];
    const float* Wq = (const float*)d_in[1];
    const float* Wk = (const float*)d_in[2];
    const float* Wv = (const float*)d_in[3];
    const float* Wo = (const float*)d_in[4];
    const float* bo = (const float*)d_in[5];
    const float* w  = (const float*)d_in[6];
    const float* v  = (const float*)d_in[7];
    float* out = (float*)d_out;

    char* w8 = (char*)d_ws;
    u16*  xb   = (u16*)(w8);                     //  8 MB : x bf16 [4096][1024]
    u16*  Wcat = (u16*)(w8 + (8u << 20));        //  6 MB : (Wq|Wk|Wv)^T bf16 [3072][1024]
    u16*  Wot  = (u16*)(w8 + (14u << 20));       //  2 MB : Wo^T bf16 [1024][1024]
    u16*  qkb  = (u16*)(w8 + (16u << 20));       // 16 MB : Q|K bf16 [4096][2048]
    u16*  vtb  = (u16*)(w8 + (32u << 20));       //  8 MB : V^T bf16 [1024][4096]
    u16*  ctxb = (u16*)(w8 + (40u << 20));       //  8 MB : ctx bf16 [4096][1024]
    float* rtab = (float*)(w8 + (48u << 20));    // 128 KB: R_hat/8 [16][2048]
    u32*  counter = (u32*)(w8 + (48u << 20) + (1u << 17));  // 4 B : job counter

    cast_kernel<<<4096, 256, 0, stream>>>(x, xb, 1048576);
    transpose4<<<dim3(32, 32, 4), 256, 0, stream>>>(Wq, Wk, Wv, Wo, Wcat, Wot);
    rtab_kernel<<<128, 256, 0, stream>>>(w, v, rtab, counter);

    // QKV fused projection -> bf16 qkb + transposed V   [M=4096, N=3072, K=1024]
    gemm128<1, 128><<<dim3(24, 32), 256, 0, stream>>>(xb, Wcat, nullptr, nullptr, qkb, vtb,
                                                      4096, 3072, 1024);
    // MFMA flash attention: 768 persistent blocks (3/CU), work-stealing
    attn_kernel<<<768, 256, 0, stream>>>(qkb, vtb, rtab, ctxb, counter);
    // output projection + bias (fp32 out)   [M=4096, N=1024, K=1024], 128x64 tiles
    gemm128<0, 64><<<dim3(16, 32), 256, 0, stream>>>(ctxb, Wot, out, bo, nullptr, nullptr,
                                                     4096, 1024, 1024);
}

// Round 6
// 193.315 us; speedup vs baseline: 1.1712x; 1.0172x over previous
//
#include <hip/hip_runtime.h>

typedef unsigned short u16;
typedef unsigned int u32;
typedef __attribute__((ext_vector_type(8))) short bf16x8;
typedef __attribute__((ext_vector_type(4))) float f32x4;

__device__ __forceinline__ u16 f2bf(float f) {
    u32 u = __float_as_uint(f);
    u += 0x7fffu + ((u >> 16) & 1u);
    return (u16)(u >> 16);
}

// async global->LDS DMA, 16B per lane, LDS dest = wave-uniform base + lane*16
#define GL2LDS(gp, lp)                                                                 \
    __builtin_amdgcn_global_load_lds((const __attribute__((address_space(1))) u32*)(const void*)(gp), \
                                     (__attribute__((address_space(3))) u32*)(void*)(lp), 16, 0, 0)

// ---------------- cast fp32 -> bf16 (vectorized x4) ----------------
__global__ __launch_bounds__(256) void cast_kernel(const float* __restrict__ src,
                                                   u16* __restrict__ dst, int n4) {
    int i = blockIdx.x * 256 + threadIdx.x;
    if (i >= n4) return;
    float4 val = ((const float4*)src)[i];
    uint2 o;
    o.x = ((u32)f2bf(val.y) << 16) | f2bf(val.x);
    o.y = ((u32)f2bf(val.w) << 16) | f2bf(val.z);
    ((uint2*)dst)[i] = o;
}

// ---------------- transpose+cast all 4 weight matrices in one launch ----------------
__global__ __launch_bounds__(256) void transpose4(const float* __restrict__ Wq,
                                                  const float* __restrict__ Wk,
                                                  const float* __restrict__ Wv,
                                                  const float* __restrict__ Wo,
                                                  u16* __restrict__ Wcat,
                                                  u16* __restrict__ Wot) {
    __shared__ float tl[32][33];
    const int zi = blockIdx.z;
    const float* src = (zi == 0) ? Wq : (zi == 1) ? Wk : (zi == 2) ? Wv : Wo;
    u16* dst = (zi < 3) ? (Wcat + zi * 1048576) : Wot;
    const int tx = threadIdx.x & 31, ty = threadIdx.x >> 5;
    const int kt = blockIdx.y * 32, nt = blockIdx.x * 32;
#pragma unroll
    for (int j = 0; j < 4; ++j)
        tl[ty + j * 8][tx] = src[(kt + ty + j * 8) * 1024 + nt + tx];
    __syncthreads();
#pragma unroll
    for (int j = 0; j < 4; ++j)
        dst[(nt + ty + j * 8) * 1024 + kt + tx] = f2bf(tl[tx][ty + j * 8]);
}

// ---------------- bf16 transpose: vrow [4096][1024] -> vtb [1024][4096] ----------------
__global__ __launch_bounds__(256) void transpose_v(const u16* __restrict__ src,
                                                   u16* __restrict__ dst) {
    __shared__ u16 tl[64][68];
    const int t = threadIdx.x, tx = t & 15, ty = t >> 4;
    const int rt = blockIdx.y * 64, ct = blockIdx.x * 64;
#pragma unroll
    for (int j = 0; j < 4; ++j) {
        const int row = ty + j * 16;
        uint2 vv = *(const uint2*)(src + (size_t)(rt + row) * 1024 + ct + tx * 4);
        tl[row][tx * 4 + 0] = (u16)(vv.x & 0xffff);
        tl[row][tx * 4 + 1] = (u16)(vv.x >> 16);
        tl[row][tx * 4 + 2] = (u16)(vv.y & 0xffff);
        tl[row][tx * 4 + 3] = (u16)(vv.y >> 16);
    }
    __syncthreads();
#pragma unroll
    for (int j = 0; j < 4; ++j) {
        const int c = ty + j * 16;
        uint2 o;
        o.x = (u32)tl[tx * 4 + 0][c] | ((u32)tl[tx * 4 + 1][c] << 16);
        o.y = (u32)tl[tx * 4 + 2][c] | ((u32)tl[tx * 4 + 3][c] << 16);
        *(uint2*)(dst + (size_t)(ct + c) * 4096 + rt + tx * 4) = o;
    }
}

// ------- R_hat table: tab[h][dist] = (1+e^v)/(1+e^(v-w*dist))/sqrt(64); also zeroes job counter -----
__global__ __launch_bounds__(256) void rtab_kernel(const float* __restrict__ wp,
                                                   const float* __restrict__ vp,
                                                   float* __restrict__ tab,
                                                   u32* __restrict__ counter) {
    const int i = blockIdx.x * 256 + threadIdx.x;  // 16*2048
    if (i == 0) counter[0] = 0u;                   // work-stealing counter for attn
    const int h = i >> 11, d = i & 2047;
    const float vv = vp[h], ww = wp[h];
    tab[i] = (1.f + expf(vv)) / (1.f + expf(vv - ww * (float)d)) * 0.125f;
}

// ---------------- m97-style bf16 MFMA GEMM: 128xBN tile, BK=64, global_load_lds ------
// C = A[M][K] @ Bt[N][K]^T.  LDS tiles unpadded, XOR-swizzled (chunk ^= row&7).
// MODE 0: fp32 out + bias.
// MODE 1: col<2048 -> Cb bf16 [M][2048] (Q|K); col>=2048 -> Vrow bf16 [M][1024] (V row-major).
template <int MODE, int BN>
__global__ __launch_bounds__(256, 3) void gemm128(const u16* __restrict__ A,
                                                  const u16* __restrict__ Bt,
                                                  float* __restrict__ C,
                                                  const float* __restrict__ bias,
                                                  u16* __restrict__ Cb,
                                                  u16* __restrict__ Vrow,
                                                  int M, int N, int K) {
    constexpr int NBW = BN / 32;  // 16-wide n-blocks per wave
    __shared__ __align__(16) u16 As[8192];      // 128 rows x 64
    __shared__ __align__(16) u16 Bs[BN * 64];   // BN rows x 64
    const int t = threadIdx.x, lane = t & 63, wv = t >> 6;
    const int l15 = lane & 15, quad = lane >> 4;
    const int m0 = blockIdx.y << 7, n0 = blockIdx.x * BN;
    const int wm = (wv & 1) << 6, wn = (wv >> 1) * (BN / 2);

    f32x4 acc[4][NBW];
#pragma unroll
    for (int i = 0; i < 4; ++i)
#pragma unroll
        for (int j = 0; j < NBW; ++j) acc[i][j] = (f32x4){0.f, 0.f, 0.f, 0.f};

    const int lrow = lane >> 3, lchunk = lane & 7;
    for (int k0 = 0; k0 < K; k0 += 64) {
#pragma unroll
        for (int c = 0; c < 4; ++c) {  // A: 128 rows
            const int r0 = wv * 32 + c * 8;
            const int row = r0 + lrow;
            const int g = lchunk ^ (row & 7);
            GL2LDS(A + (size_t)(m0 + row) * K + k0 + g * 8, &As[r0 * 64]);
        }
#pragma unroll
        for (int c = 0; c < BN / 32; ++c) {  // B: BN rows
            const int r0 = wv * (BN / 4) + c * 8;
            const int row = r0 + lrow;
            const int g = lchunk ^ (row & 7);
            GL2LDS(Bt + (size_t)(n0 + row) * K + k0 + g * 8, &Bs[r0 * 64]);
        }
        __syncthreads();  // drains global_load_lds (vmcnt) + protects prior reads
#pragma unroll
        for (int ks = 0; ks < 2; ++ks) {
            const int p = ((ks << 2) | quad) ^ (l15 & 7);
            bf16x8 af[4], bfr[NBW];
#pragma unroll
            for (int i = 0; i < 4; ++i)
                af[i] = *(const bf16x8*)&As[(wm + i * 16 + l15) * 64 + p * 8];
#pragma unroll
            for (int j = 0; j < NBW; ++j)
                bfr[j] = *(const bf16x8*)&Bs[(wn + j * 16 + l15) * 64 + p * 8];
#pragma unroll
            for (int mb = 0; mb < 4; ++mb)
#pragma unroll
                for (int nb = 0; nb < NBW; ++nb)
                    acc[mb][nb] = __builtin_amdgcn_mfma_f32_16x16x32_bf16(af[mb], bfr[nb],
                                                                          acc[mb][nb], 0, 0, 0);
        }
        __syncthreads();  // protect LDS before next stage overwrites
    }
    // epilogue: C/D layout col=lane&15, row=(lane>>4)*4+reg
    const int rb = m0 + wm + (quad << 2);
    const int cbase = n0 + wn + l15;
#pragma unroll
    for (int mb = 0; mb < 4; ++mb)
#pragma unroll
        for (int nb = 0; nb < NBW; ++nb) {
            const int col = cbase + nb * 16;
#pragma unroll
            for (int r = 0; r < 4; ++r) {
                const int row = rb + mb * 16 + r;
                if (MODE == 0) {
                    C[(size_t)row * N + col] = acc[mb][nb][r] + bias[col];
                } else {
                    if (col < 2048)
                        Cb[(size_t)row * 2048 + col] = f2bf(acc[mb][nb][r]);
                    else
                        Vrow[(size_t)row * 1024 + (col - 2048)] = f2bf(acc[mb][nb][r]);
                }
            }
        }
}

// ---------------- MFMA flash attention v5: S-transposed, 1 barrier/iter ----------------
// Computes S^T = K @ Q^T (C-layout: lane owns column q=l15, rows kseq=quad*4+r), so
// softmax l is a per-lane scalar and P stays in registers: PV = V^T @ P^T where the
// B-operand k-halves are assigned to whole S^T blocks -> B-frag == lane's own packs.
// qkb: bf16 [4096][2048] (Q|K).  vtb: bf16 [1024][4096] (V^T).  rtab fp32 [16][2048].
// Persistent 768 blocks (3/CU) + work-stealing, longest-first.
__global__ __launch_bounds__(256, 3) void attn_kernel(const u16* __restrict__ qkb,
                                                      const u16* __restrict__ vtb,
                                                      const float* __restrict__ rtab,
                                                      u16* __restrict__ ctxb,
                                                      u32* __restrict__ counter) {
    __shared__ __align__(16) u16 Kt[2][4096];   // [kseq][d] swizzled, 8KB x2
    __shared__ __align__(16) u16 Vt2[2][4096];  // [d][kseq] swizzled, 8KB x2
    __shared__ float rall[2048];                // R_hat/8 row for this head
    __shared__ int jobS;

    const int t = threadIdx.x, lane = t & 63, wv = t >> 6;
    const int l15 = lane & 15, quad = lane >> 4;
    const int lrow = lane >> 3, lchunk = lane & 7;
    const int half0 = (wv & 1) * 32;

    for (;;) {
        if (t == 0) jobS = (int)atomicAdd(counter, 1u);
        __syncthreads();       // jobS visible; fences prior job's LDS reads
        const int job = jobS;
        if (job >= 1024) break;
        const int qt = 31 - (job >> 5);       // longest jobs first
        const int bh = job & 31;
        const int b = bh >> 4, h = bh & 15;
        const int q0 = qt << 6;

        for (int i = t; i < q0 + 64; i += 256) rall[i] = rtab[(h << 11) + i];

        // Q as B-operand fragments for S^T: lane n=l15 -> q = q0+wv*16+l15, k=d
        bf16x8 qb[2];
        {
            const u16* qrow = qkb + (size_t)(b * 2048 + q0 + (wv << 4) + l15) * 2048 +
                              (h << 6) + quad * 8;
            qb[0] = *(const bf16x8*)(qrow);
            qb[1] = *(const bf16x8*)(qrow + 32);
        }

        f32x4 cacc[4];   // ctx^T accum: db d-blocks, lane holds (d=quad*4+r, q=l15)
#pragma unroll
        for (int i = 0; i < 4; ++i) cacc[i] = (f32x4){0.f, 0.f, 0.f, 0.f};
        float lacc = 0.f;  // per-lane partial softmax denom for column q=l15

        // stage kt=0 into buffer 0 (waves 0,1: K; waves 2,3: V^T)
#pragma unroll
        for (int c = 0; c < 4; ++c) {
            const int r0 = half0 + c * 8;
            const int row = r0 + lrow;
            const int g = lchunk ^ (row & 7);
            if (wv < 2)
                GL2LDS(qkb + (size_t)(b * 2048 + row) * 2048 + 1024 + (h << 6) + g * 8,
                       &Kt[0][r0 * 64]);
            else
                GL2LDS(vtb + (size_t)((h << 6) + row) * 4096 + b * 2048 + g * 8,
                       &Vt2[0][r0 * 64]);
        }

        for (int kt = 0; kt <= qt; ++kt) {
            const int bsel = kt & 1;
            __syncthreads();  // drains staging of buf[bsel] (vmcnt) + orders LDS reuse
            if (kt < qt) {    // prefetch kt+1 into other buffer
                const int kg0 = (kt + 1) << 6;
#pragma unroll
                for (int c = 0; c < 4; ++c) {
                    const int r0 = half0 + c * 8;
                    const int row = r0 + lrow;
                    const int g = lchunk ^ (row & 7);
                    if (wv < 2)
                        GL2LDS(qkb + (size_t)(b * 2048 + kg0 + row) * 2048 + 1024 + (h << 6) + g * 8,
                               &Kt[bsel ^ 1][r0 * 64]);
                    else
                        GL2LDS(vtb + (size_t)((h << 6) + row) * 4096 + b * 2048 + kg0 + g * 8,
                               &Vt2[bsel ^ 1][r0 * 64]);
                }
            }

            // ---- S^T = K @ Q^T : 64 kseq x 16 q per wave (8 MFMA), A=K from LDS ----
            f32x4 sacc[4];
#pragma unroll
            for (int i = 0; i < 4; ++i) sacc[i] = (f32x4){0.f, 0.f, 0.f, 0.f};
#pragma unroll
            for (int ks = 0; ks < 2; ++ks) {
                const int p = ((ks << 2) | quad) ^ (l15 & 7);
#pragma unroll
                for (int mb = 0; mb < 4; ++mb) {
                    bf16x8 ka = *(const bf16x8*)&Kt[bsel][(mb * 16 + l15) * 64 + p * 8];
                    sacc[mb] = __builtin_amdgcn_mfma_f32_16x16x32_bf16(ka, qb[ks],
                                                                       sacc[mb], 0, 0, 0);
                }
            }

            // ---- gate + exp (fixed m=0), per-lane l accum, pack P to bf16 regs ----
            // lane value (mb,r): q = q0+wv*16+l15, kseq = kg0+mb*16+quad*4+r
            const int D0 = q0 - (kt << 6) + (wv << 4) + l15;  // q - kg0 - local kseq base
            u32 pk[4][2];
            if (kt < qt) {  // off-diagonal: dist >= 1 guaranteed
#pragma unroll
                for (int mb = 0; mb < 4; ++mb) {
                    float pe[4];
#pragma unroll
                    for (int r = 0; r < 4; ++r) {
                        const int dist = D0 - (mb * 16 + (quad << 2) + r);
                        pe[r] = __expf(fmaxf(sacc[mb][r], 0.f) * rall[dist]);
                        lacc += pe[r];
                    }
                    pk[mb][0] = (__float_as_uint(pe[0]) >> 16) |
                                (__float_as_uint(pe[1]) & 0xffff0000u);
                    pk[mb][1] = (__float_as_uint(pe[2]) >> 16) |
                                (__float_as_uint(pe[3]) & 0xffff0000u);
                }
            } else {  // diagonal tile: causal mask (dist<0 -> 0)
#pragma unroll
                for (int mb = 0; mb < 4; ++mb) {
                    float pe[4];
#pragma unroll
                    for (int r = 0; r < 4; ++r) {
                        const int dist = D0 - (mb * 16 + (quad << 2) + r);
                        const int di = dist < 0 ? 0 : dist;
                        float p0 = __expf(fmaxf(sacc[mb][r], 0.f) * rall[di]);
                        pe[r] = (dist < 0) ? 0.f : p0;
                        lacc += pe[r];
                    }
                    pk[mb][0] = (__float_as_uint(pe[0]) >> 16) |
                                (__float_as_uint(pe[1]) & 0xffff0000u);
                    pk[mb][1] = (__float_as_uint(pe[2]) >> 16) |
                                (__float_as_uint(pe[3]) & 0xffff0000u);
                }
            }

            // ---- ctx^T += V^T @ P^T : 8 MFMA, B-frag = own packed P regs ----
            // call ks covers S^T blocks X=2ks (k j=0..3) and Y=2ks+1 (k j=4..7);
            // A-frag k-order matches: V^T[d][X*16+quad*4+j | Y*16+quad*4+(j-4)]
#pragma unroll
            for (int ks = 0; ks < 2; ++ks) {
                int4 pv = {(int)pk[2 * ks][0], (int)pk[2 * ks][1],
                           (int)pk[2 * ks + 1][0], (int)pk[2 * ks + 1][1]};
                bf16x8 pb = *(bf16x8*)&pv;
                const int gA = (4 * ks + (quad >> 1)) ^ (l15 & 7);
                const int gB = (4 * ks + 2 + (quad >> 1)) ^ (l15 & 7);
                const int off = (quad & 1) * 4;
#pragma unroll
                for (int db = 0; db < 4; ++db) {
                    const u16* base = &Vt2[bsel][(db * 16 + l15) * 64];
                    uint2 va = *(const uint2*)(base + gA * 8 + off);
                    uint2 vb = *(const uint2*)(base + gB * 8 + off);
                    int4 vv = {(int)va.x, (int)va.y, (int)vb.x, (int)vb.y};
                    bf16x8 vf = *(bf16x8*)&vv;
                    cacc[db] = __builtin_amdgcn_mfma_f32_16x16x32_bf16(vf, pb,
                                                                       cacc[db], 0, 0, 0);
                }
            }
        }

        // ---- epilogue: l = quad-column reduce; normalize; store ctx (8B/store) ----
        float lt = lacc;
        lt += __shfl_xor(lt, 16, 64);
        lt += __shfl_xor(lt, 32, 64);
        const float inv = 1.f / lt;
        u16* op = ctxb + (size_t)(b * 2048 + q0 + (wv << 4) + l15) * 1024 +
                  (h << 6) + (quad << 2);
#pragma unroll
        for (int db = 0; db < 4; ++db) {
            uint2 o;
            o.x = (u32)f2bf(cacc[db][0] * inv) | ((u32)f2bf(cacc[db][1] * inv) << 16);
            o.y = (u32)f2bf(cacc[db][2] * inv) | ((u32)f2bf(cacc[db][3] * inv) << 16);
            *(uint2*)(op + db * 16) = o;
        }
        // loop-top __syncthreads() fences these LDS reads before next job's writes
    }
}

extern "C" void kernel_launch(void* const* d_in, const int* in_sizes, int n_in,
                              void* d_out, int out_size, void* d_ws, size_t ws_size,
                              hipStream_t stream) {
    const float* x  = (const float*)d_in[0];
    const float* Wq = (const float*)d_in[1];
    const float* Wk = (const float*)d_in[2];
    const float* Wv = (const float*)d_in[3];
    const float* Wo = (const float*)d_in[4];
    const float* bo = (const float*)d_in[5];
    const float* w  = (const float*)d_in[6];
    const float* v  = (const float*)d_in[7];
    float* out = (float*)d_out;

    char* w8 = (char*)d_ws;
    u16*  xb   = (u16*)(w8);                     //  8 MB : x bf16 [4096][1024]
    u16*  Wcat = (u16*)(w8 + (8u << 20));        //  6 MB : (Wq|Wk|Wv)^T bf16 [3072][1024]
    u16*  Wot  = (u16*)(w8 + (14u << 20));       //  2 MB : Wo^T bf16 [1024][1024]
    u16*  qkb  = (u16*)(w8 + (16u << 20));       // 16 MB : Q|K bf16 [4096][2048]
    u16*  vtb  = (u16*)(w8 + (32u << 20));       //  8 MB : V^T bf16 [1024][4096]
    u16*  ctxb = (u16*)(w8 + (40u << 20));       //  8 MB : ctx bf16 [4096][1024]
    float* rtab = (float*)(w8 + (48u << 20));    // 128 KB: R_hat/8 [16][2048]
    u32*  counter = (u32*)(w8 + (48u << 20) + (1u << 17));  // 4 B : job counter
    u16*  vrow = (u16*)(w8 + (49u << 20));       //  8 MB : V bf16 row-major [4096][1024]

    cast_kernel<<<4096, 256, 0, stream>>>(x, xb, 1048576);
    transpose4<<<dim3(32, 32, 4), 256, 0, stream>>>(Wq, Wk, Wv, Wo, Wcat, Wot);
    rtab_kernel<<<128, 256, 0, stream>>>(w, v, rtab, counter);

    // QKV fused projection -> bf16 qkb (Q|K) + V row-major   [M=4096, N=3072, K=1024]
    gemm128<1, 128><<<dim3(24, 32), 256, 0, stream>>>(xb, Wcat, nullptr, nullptr, qkb, vrow,
                                                      4096, 3072, 1024);
    // V row-major -> V^T (coalesced both sides)
    transpose_v<<<dim3(16, 64), 256, 0, stream>>>(vrow, vtb);
    // MFMA flash attention: 768 persistent blocks (3/CU), work-stealing
    attn_kernel<<<768, 256, 0, stream>>>(qkb, vtb, rtab, ctxb, counter);
    // output projection + bias (fp32 out)   [M=4096, N=1024, K=1024], 128x64 tiles
    gemm128<0, 64><<<dim3(16, 32), 256, 0, stream>>>(ctxb, Wot, out, bo, nullptr, nullptr,
                                                     4096, 1024, 1024);
}